// Round 7
// baseline (581.561 us; speedup 1.0000x reference)
//
#include <hip/hip_runtime.h>
#include <hip/hip_bf16.h>
#include <math.h>

typedef __bf16 bf16;
typedef __bf16 bf16x8 __attribute__((ext_vector_type(8)));
typedef __bf16 bf16x4 __attribute__((ext_vector_type(4)));
typedef float  f32x4  __attribute__((ext_vector_type(4)));

#define C_    384
#define NH_   12
#define HD_   32
#define MLP_  1536
#define B_    8
#define T_    12
#define N_    256
#define BT_   96
#define M_    24576
#define NINE_C 3456
#define QKV_  1152

#define GLOAD16(gptr, lptr)                                                \
  __builtin_amdgcn_global_load_lds(                                       \
      (const __attribute__((address_space(1))) void*)(gptr),              \
      (__attribute__((address_space(3))) void*)(lptr), 16, 0, 0)

__device__ __forceinline__ float wave_sum(float v) {
#pragma unroll
  for (int o = 32; o > 0; o >>= 1) v += __shfl_xor(v, o, 64);
  return v;
}

template <typename TO> __device__ __forceinline__ TO to_out(float v);
template <> __device__ __forceinline__ float to_out<float>(float v) { return v; }
template <> __device__ __forceinline__ bf16  to_out<bf16>(float v)  { return (bf16)v; }

// ---------- all f32 -> bf16 weight conversions in one kernel ----------
struct F2BArgs {
  const float* src[7];
  bf16* dst[7];
  int n4[7];
};
__global__ __launch_bounds__(256) void k_f2b_all(F2BArgs a) {
  const int seg = blockIdx.y;
  const int i = blockIdx.x * 256 + threadIdx.x;
  if (i < a.n4[seg]) {
    float4 v = ((const float4*)a.src[seg])[i];
    bf16x4 o;
    o[0] = (bf16)v.x; o[1] = (bf16)v.y; o[2] = (bf16)v.z; o[3] = (bf16)v.w;
    ((bf16x4*)a.dst[seg])[i] = o;
  }
}

// ---------- silu(c) -> bf16, padded to 128 rows ----------
__global__ __launch_bounds__(384) void k_silu(const float* __restrict__ c,
                                              bf16* __restrict__ out) {
  const int row = blockIdx.x, tid = threadIdx.x;
  float v = 0.f;
  if (row < BT_) {
    float cv = c[row * C_ + tid];
    v = cv / (1.f + __expf(-cv));
  }
  out[row * C_ + tid] = (bf16)v;
}

// ---------- LayerNorm + adaLN modulate -> bf16 ----------
__global__ __launch_bounds__(256) void k_ln_mod(const float* __restrict__ x,
                                                const float* __restrict__ mod,
                                                bf16* __restrict__ out,
                                                int shift_chunk, int scale_chunk) {
  const int wave = threadIdx.x >> 6, lane = threadIdx.x & 63;
  const int r = blockIdx.x * 4 + wave;
  const float* xr = x + (size_t)r * C_;
  float v[6];
  float s = 0.f, ss = 0.f;
#pragma unroll
  for (int e = 0; e < 6; ++e) { v[e] = xr[lane + 64 * e]; s += v[e]; ss += v[e] * v[e]; }
  s = wave_sum(s); ss = wave_sum(ss);
  const float mean = s * (1.f / C_);
  const float var  = ss * (1.f / C_) - mean * mean;
  const float rs   = rsqrtf(var + 1e-6f);
  const int bt = r >> 8;
  const float* sh = mod + (size_t)bt * NINE_C + shift_chunk * C_;
  const float* sc = mod + (size_t)bt * NINE_C + scale_chunk * C_;
  bf16* orow = out + (size_t)r * C_;
#pragma unroll
  for (int e = 0; e < 6; ++e) {
    int cc = lane + 64 * e;
    orow[cc] = (bf16)((v[e] - mean) * rs * (1.f + sc[cc]) + sh[cc]);
  }
}

// ---------- temporal LN + modulate (gather) -> bf16 ----------
__global__ __launch_bounds__(256) void k_ln_mod_t(const float* __restrict__ x,
                                                  const float* __restrict__ mod,
                                                  bf16* __restrict__ out) {
  const int wave = threadIdx.x >> 6, lane = threadIdx.x & 63;
  const int rr = blockIdx.x * 4 + wave;          // rr = bn*12 + t
  const int bn = rr / T_, t = rr - bn * T_;
  const int b = bn >> 8, n = bn & 255;
  const int in_row = (b * T_ + t) * N_ + n;
  const int mrow   = b * T_ + t;
  const float* xr = x + (size_t)in_row * C_;
  float v[6];
  float s = 0.f, ss = 0.f;
#pragma unroll
  for (int e = 0; e < 6; ++e) { v[e] = xr[lane + 64 * e]; s += v[e]; ss += v[e] * v[e]; }
  s = wave_sum(s); ss = wave_sum(ss);
  const float mean = s * (1.f / C_);
  const float var  = ss * (1.f / C_) - mean * mean;
  const float rs   = rsqrtf(var + 1e-6f);
  const float* sh = mod + (size_t)mrow * NINE_C + 3 * C_;
  const float* sc = mod + (size_t)mrow * NINE_C + 4 * C_;
  bf16* orow = out + (size_t)rr * C_;
#pragma unroll
  for (int e = 0; e < 6; ++e) {
    int cc = lane + 64 * e;
    orow[cc] = (bf16)((v[e] - mean) * rs * (1.f + sc[cc]) + sh[cc]);
  }
}

// ================= persistent-W pipelined GEMM (K=384 only) ==================
// 256 thr, 4 waves (2x2), wave tile 64x64. W[n0..n0+127][384] resident in LDS
// (96 KB, swizzled). A K-slices (128x64 = 16 KB) double-buffered; counted
// vmcnt(4) + raw s_barrier pipeline, 1 block/CU (128 KB dynamic LDS).
// EPI 0 plain / 1 GELU / 2 gated residual / 3 temporal scatter residual.
template <typename TO, int EPI>
__global__ __launch_bounds__(256, 1)
void gemm_pw(const bf16* __restrict__ A, const bf16* __restrict__ W,
             const float* __restrict__ bias, TO* __restrict__ out,
             int MT, int N,
             const float* __restrict__ base, const float* __restrict__ mod,
             int gc, int ntx, int ngroups) {
  extern __shared__ char smem[];           // [W 96K][A0 16K][A1 16K]
  char* Ab0 = smem + 98304;
  char* Ab1 = smem + 114688;
  const int tid = threadIdx.x;
  const int w = tid >> 6, l = tid & 63;
  // bijective XCD swizzle: consecutive logical t -> same XCD (share A panels)
  const int nwg = ntx * ngroups;
  const int q8 = nwg >> 3, r8 = nwg & 7;
  const int xcd = blockIdx.x & 7, bidx = blockIdx.x >> 3;
  const int t = (xcd < r8 ? xcd * (q8 + 1) : r8 * (q8 + 1) + (xcd - r8) * q8) + bidx;
  const int n0 = (t % ntx) * 128;
  const int g  = t / ntx;
  const int nmt = (MT - g + ngroups - 1) / ngroups;
  const int wr = w >> 1, wc = w & 1;

  // ---- stage W once: 24 gload16 per lane (per-wave 1KB granules) ----
#pragma unroll
  for (int j = 0; j < 24; ++j) {
    int ci = (j * 4 + w) * 64 + l;         // chunk index 0..6143
    int r = ci / 48, p = ci - r * 48;      // row 0..127, chunk 0..47
    int sc = p ^ (r & 7);
    GLOAD16(W + (size_t)(n0 + r) * 384 + sc * 8, smem + (j * 4 + w) * 1024);
  }
  // ---- stage first A slice into buf0 ----
  {
    int mt0 = g;
#pragma unroll
    for (int i = 0; i < 4; ++i) {
      int ci = (i * 4 + w) * 64 + l;
      int r = ci >> 3, p = ci & 7;
      int sc = p ^ (r & 7);
      GLOAD16(A + (size_t)(mt0 * 128 + r) * 384 + sc * 8, Ab0 + (i * 4 + w) * 1024);
    }
  }

  f32x4 acc[4][4];
  const int total = nmt * 6;
  for (int s = 0; s < total; ++s) {
    const int ti = s / 6, k = s - ti * 6;
    const int mt = g + ti * ngroups;
    if (s + 1 < total) {
      const int s2 = s + 1;
      const int ti2 = s2 / 6, k2 = s2 - ti2 * 6;
      const int mt2 = g + ti2 * ngroups;
      char* dst = (s2 & 1) ? Ab1 : Ab0;
#pragma unroll
      for (int i = 0; i < 4; ++i) {
        int ci = (i * 4 + w) * 64 + l;
        int r = ci >> 3, p = ci & 7;
        int sc = p ^ (r & 7);
        GLOAD16(A + (size_t)(mt2 * 128 + r) * 384 + k2 * 64 + sc * 8,
                dst + (i * 4 + w) * 1024);
      }
      asm volatile("s_waitcnt vmcnt(4)" ::: "memory");
    } else {
      asm volatile("s_waitcnt vmcnt(0)" ::: "memory");
    }
    __builtin_amdgcn_s_barrier();
    asm volatile("" ::: "memory");

    if (k == 0) {
#pragma unroll
      for (int mi = 0; mi < 4; ++mi)
#pragma unroll
        for (int nj = 0; nj < 4; ++nj) acc[mi][nj] = (f32x4){0.f, 0.f, 0.f, 0.f};
    }
    const char* Ac = (s & 1) ? Ab1 : Ab0;
#pragma unroll
    for (int kt = 0; kt < 2; ++kt) {
      bf16x8 a[4], b[4];
      const int cc = kt * 4 + (l >> 4);
      const int gch = k * 8 + cc;            // W chunk within full K row
#pragma unroll
      for (int mi = 0; mi < 4; ++mi) {
        int row = wr * 64 + mi * 16 + (l & 15);
        a[mi] = *(const bf16x8*)(Ac + row * 128 + ((cc ^ (row & 7)) << 4));
      }
#pragma unroll
      for (int nj = 0; nj < 4; ++nj) {
        int row = wc * 64 + nj * 16 + (l & 15);
        b[nj] = *(const bf16x8*)(smem + row * 768 + ((gch ^ (row & 7)) << 4));
      }
#pragma unroll
      for (int mi = 0; mi < 4; ++mi)
#pragma unroll
        for (int nj = 0; nj < 4; ++nj)
          acc[mi][nj] = __builtin_amdgcn_mfma_f32_16x16x32_bf16(a[mi], b[nj], acc[mi][nj], 0, 0, 0);
    }

    if (k == 5) {
      const int m0 = mt * 128;
      const int btc = m0 >> 8;
#pragma unroll
      for (int nj = 0; nj < 4; ++nj) {
        int col = n0 + wc * 64 + nj * 16 + (l & 15);
        float bv = bias[col];
        float gv = 0.f;
        if (EPI == 2) gv = mod[(size_t)btc * NINE_C + gc * C_ + col];
#pragma unroll
        for (int mi = 0; mi < 4; ++mi) {
#pragma unroll
          for (int q = 0; q < 4; ++q) {
            int rrow = m0 + wr * 64 + mi * 16 + (l >> 4) * 4 + q;
            float v = acc[mi][nj][q] + bv;
            if (EPI == 0) {
              out[(size_t)rrow * N + col] = to_out<TO>(v);
            } else if (EPI == 1) {
              v = 0.5f * v * (1.f + erff(v * 0.70710678118654752f));
              out[(size_t)rrow * N + col] = to_out<TO>(v);
            } else if (EPI == 2) {
              ((float*)out)[(size_t)rrow * N + col] =
                  base[(size_t)rrow * N + col] + gv * v;
            } else {
              int b2 = rrow / 3072;
              int rem = rrow - b2 * 3072;
              int n = rem / 12, tt = rem - n * 12;
              int btd = b2 * 12 + tt;
              size_t dst = ((size_t)btd * 256 + n) * N + col;
              float g2 = mod[(size_t)btd * NINE_C + 5 * C_ + col];
              ((float*)out)[dst] += g2 * v;
            }
          }
        }
      }
    }
    asm volatile("" ::: "memory");
    __builtin_amdgcn_s_barrier();
    asm volatile("" ::: "memory");
  }
}

// ---------- old 2-barrier MFMA GEMM (kept for K=1536 MLP2) ----------
template <typename TO, int EPI>
__global__ __launch_bounds__(256) void mfma_gemm(const bf16* __restrict__ A,
                                                 const bf16* __restrict__ W,
                                                 const float* __restrict__ bias,
                                                 TO* __restrict__ out,
                                                 int M, int N, int K,
                                                 const float* __restrict__ base,
                                                 const float* __restrict__ mod,
                                                 int gc, int ntx) {
  __shared__ bf16 As[128 * 64];
  __shared__ bf16 Bs[128 * 64];
  const int tid = threadIdx.x;
  const int w = tid >> 6, l = tid & 63;
  const int nwg = gridDim.x;
  const int q8 = nwg >> 3, r8 = nwg & 7;
  const int xcd = blockIdx.x & 7, idx = blockIdx.x >> 3;
  const int t = (xcd < r8 ? xcd * (q8 + 1) : r8 * (q8 + 1) + (xcd - r8) * q8) + idx;
  const int m0 = (t / ntx) * 128, n0 = (t % ntx) * 128;
  const int wr = w >> 1, wc = w & 1;
  f32x4 acc[4][4];
#pragma unroll
  for (int mi = 0; mi < 4; ++mi)
#pragma unroll
    for (int nj = 0; nj < 4; ++nj) acc[mi][nj] = (f32x4){0.f, 0.f, 0.f, 0.f};

  const int srow8 = l >> 3;
  const int c8    = l & 7;

  for (int k0 = 0; k0 < K; k0 += 64) {
#pragma unroll
    for (int i = 0; i < 4; ++i) {
      int row = w * 32 + i * 8 + srow8;
      int sc = c8 ^ (row & 7);
      GLOAD16(A + (size_t)(m0 + row) * K + k0 + sc * 8,
              (char*)As + (w * 32 + i * 8) * 128);
      GLOAD16(W + (size_t)(n0 + row) * K + k0 + sc * 8,
              (char*)Bs + (w * 32 + i * 8) * 128);
    }
    __syncthreads();
#pragma unroll
    for (int kt = 0; kt < 2; ++kt) {
      bf16x8 a[4], b[4];
      const int cc = kt * 4 + (l >> 4);
#pragma unroll
      for (int mi = 0; mi < 4; ++mi) {
        int row = wr * 64 + mi * 16 + (l & 15);
        a[mi] = *(const bf16x8*)((const char*)As + row * 128 + ((cc ^ (row & 7)) << 4));
      }
#pragma unroll
      for (int nj = 0; nj < 4; ++nj) {
        int row = wc * 64 + nj * 16 + (l & 15);
        b[nj] = *(const bf16x8*)((const char*)Bs + row * 128 + ((cc ^ (row & 7)) << 4));
      }
#pragma unroll
      for (int mi = 0; mi < 4; ++mi)
#pragma unroll
        for (int nj = 0; nj < 4; ++nj)
          acc[mi][nj] = __builtin_amdgcn_mfma_f32_16x16x32_bf16(a[mi], b[nj], acc[mi][nj], 0, 0, 0);
    }
    __syncthreads();
  }
  const int btc = m0 >> 8;
#pragma unroll
  for (int nj = 0; nj < 4; ++nj) {
    int col = n0 + wc * 64 + nj * 16 + (l & 15);
    float bv = bias[col];
    float gv = 0.f;
    if (EPI == 2) gv = mod[(size_t)btc * NINE_C + gc * C_ + col];
#pragma unroll
    for (int mi = 0; mi < 4; ++mi) {
#pragma unroll
      for (int q = 0; q < 4; ++q) {
        int rrow = m0 + wr * 64 + mi * 16 + (l >> 4) * 4 + q;
        float v = acc[mi][nj][q] + bv;
        if (EPI == 0) {
          out[(size_t)rrow * N + col] = to_out<TO>(v);
        } else if (EPI == 1) {
          v = 0.5f * v * (1.f + erff(v * 0.70710678118654752f));
          out[(size_t)rrow * N + col] = to_out<TO>(v);
        } else if (EPI == 2) {
          ((float*)out)[(size_t)rrow * N + col] =
              base[(size_t)rrow * N + col] + gv * v;
        } else {
          int b = rrow / 3072;
          int rem = rrow - b * 3072;
          int n = rem / 12, tt = rem - n * 12;
          int btd = b * 12 + tt;
          size_t dst = ((size_t)btd * 256 + n) * N + col;
          float g = mod[(size_t)btd * NINE_C + 5 * C_ + col];
          ((float*)out)[dst] += g * v;
        }
      }
    }
  }
}

// ---------- fused spatial attention ----------
__global__ __launch_bounds__(256) void k_attn_fused(const bf16* __restrict__ qkv,
                                                    const float* __restrict__ bias,
                                                    float* __restrict__ attn,
                                                    bf16* __restrict__ out) {
  __shared__ bf16 Vt[32 * 256];        // [d][k], rows 512B, XOR-swizzled 16B chunks
  __shared__ bf16 Pl[4][16][260];      // per-wave P tile, padded rows (520B)
  const int blk = blockIdx.x;
  const int bt = blk / NH_, h = blk - bt * NH_;
  const int tid = threadIdx.x;
#pragma unroll
  for (int r = 0; r < 4; ++r) {
    int id = tid + 256 * r;
    int j = id >> 2, c = id & 3;
    bf16x8 vv = *(const bf16x8*)(qkv + (size_t)(bt * N_ + j) * QKV_ + 2 * C_ + h * HD_ + c * 8);
    int kc = j >> 3, ke = j & 7;
#pragma unroll
    for (int i = 0; i < 8; ++i) {
      int d = c * 8 + i;
      *(bf16*)((char*)Vt + d * 512 + ((kc ^ (d & 7)) << 4) + ke * 2) = vv[i];
    }
  }
  const int w = tid >> 6, l = tid & 63;
  const int ln = l & 15, kg = l >> 4;
  const bf16* kbase = qkv + (size_t)bt * N_ * QKV_ + C_ + h * HD_ + kg * 8;
  bf16x8 kfr[16];
#pragma unroll
  for (int nj = 0; nj < 16; ++nj)
    kfr[nj] = *(const bf16x8*)(kbase + (size_t)(nj * 16 + ln) * QKV_);
  __syncthreads();

  const float scale = 0.17677669529663687f;
  const float* bb = bias + (size_t)h * N_ * N_;
  float* Pb = attn + (size_t)blk * N_ * N_;
  const bf16* qbase = qkv + (size_t)bt * N_ * QKV_ + h * HD_ + kg * 8;
  char* Pw = (char*)&Pl[w][0][0];

  for (int g = 0; g < 4; ++g) {
    const int i0 = w * 64 + g * 16;
    bf16x8 aq = *(const bf16x8*)(qbase + (size_t)(i0 + ln) * QKV_);
    f32x4 s[16];
#pragma unroll
    for (int nj = 0; nj < 16; ++nj)
      s[nj] = __builtin_amdgcn_mfma_f32_16x16x32_bf16(aq, kfr[nj], (f32x4){0.f,0.f,0.f,0.f}, 0, 0, 0);
#pragma unroll
    for (int q = 0; q < 4; ++q) {
      const int lr = kg * 4 + q;
      const int row = i0 + lr;
      const float* br = bb + (size_t)row * N_ + ln;
      float v[16];
      float mx = -1e30f;
#pragma unroll
      for (int nj = 0; nj < 16; ++nj) {
        v[nj] = s[nj][q] * scale + br[nj * 16];
        mx = fmaxf(mx, v[nj]);
      }
#pragma unroll
      for (int o = 8; o > 0; o >>= 1) mx = fmaxf(mx, __shfl_xor(mx, o, 64));
      float sum = 0.f;
#pragma unroll
      for (int nj = 0; nj < 16; ++nj) { v[nj] = __expf(v[nj] - mx); sum += v[nj]; }
#pragma unroll
      for (int o = 8; o > 0; o >>= 1) sum += __shfl_xor(sum, o, 64);
      float inv = __frcp_rn(sum);
      float* pr = Pb + (size_t)row * N_ + ln;
#pragma unroll
      for (int nj = 0; nj < 16; ++nj) {
        float p = v[nj] * inv;
        pr[nj * 16] = p;
        *(bf16*)(Pw + lr * 520 + (ln + 16 * nj) * 2) = (bf16)p;
      }
    }
    f32x4 o0 = (f32x4){0.f,0.f,0.f,0.f}, o1 = (f32x4){0.f,0.f,0.f,0.f};
#pragma unroll
    for (int kt = 0; kt < 8; ++kt) {
      bf16x8 a = *(const bf16x8*)(Pw + ln * 520 + kt * 64 + kg * 16);
      int kc = kt * 4 + kg;
      bf16x8 b0 = *(const bf16x8*)((const char*)Vt + (size_t)ln * 512 + ((kc ^ (ln & 7)) << 4));
      bf16x8 b1 = *(const bf16x8*)((const char*)Vt + (size_t)(16 + ln) * 512 + ((kc ^ (ln & 7)) << 4));
      o0 = __builtin_amdgcn_mfma_f32_16x16x32_bf16(a, b0, o0, 0, 0, 0);
      o1 = __builtin_amdgcn_mfma_f32_16x16x32_bf16(a, b1, o1, 0, 0, 0);
    }
#pragma unroll
    for (int q = 0; q < 4; ++q) {
      int row = i0 + kg * 4 + q;
      bf16* orow = out + (size_t)(bt * N_ + row) * C_ + h * HD_;
      orow[ln]      = (bf16)o0[q];
      orow[16 + ln] = (bf16)o1[q];
    }
  }
}

// ---------- temporal attention (T=12) -> bf16 ----------
__global__ __launch_bounds__(64) void k_attn_t(const bf16* __restrict__ qkv,
                                               bf16* __restrict__ out) {
  __shared__ float q[T_][HD_], k[T_][HD_], v[T_][HD_];
  const int blk = blockIdx.x;
  const int bn = blk / NH_, h = blk - bn * NH_;
  const int tid = threadIdx.x;
  for (int idx = tid; idx < T_ * 3 * HD_; idx += 64) {
    int t = idx / 96, rem = idx - t * 96;
    int s = rem >> 5, d = rem & 31;
    float val = (float)qkv[(size_t)(bn * T_ + t) * QKV_ + s * C_ + h * HD_ + d];
    if (s == 0) q[t][d] = val;
    else if (s == 1) k[t][d] = val;
    else v[t][d] = val;
  }
  __syncthreads();
  if (tid < T_) {
    const int i = tid;
    float sv[T_];
    float m = -1e30f;
#pragma unroll
    for (int j = 0; j < T_; ++j) {
      float s = 0.f;
#pragma unroll
      for (int d = 0; d < HD_; ++d) s += q[i][d] * k[j][d];
      s *= 0.17677669529663687f;
      sv[j] = s; m = fmaxf(m, s);
    }
    float l = 0.f;
#pragma unroll
    for (int j = 0; j < T_; ++j) { sv[j] = __expf(sv[j] - m); l += sv[j]; }
    const float inv = 1.f / l;
    float o[HD_];
#pragma unroll
    for (int d = 0; d < HD_; ++d) o[d] = 0.f;
#pragma unroll
    for (int j = 0; j < T_; ++j)
#pragma unroll
      for (int d = 0; d < HD_; ++d) o[d] += sv[j] * v[j][d];
    bf16* orow = out + (size_t)(bn * T_ + i) * C_ + h * HD_;
#pragma unroll
    for (int d = 0; d < HD_; ++d) orow[d] = (bf16)(o[d] * inv);
  }
}

extern "C" void kernel_launch(void* const* d_in, const int* in_sizes, int n_in,
                              void* d_out, int out_size, void* d_ws, size_t ws_size,
                              hipStream_t stream) {
  const float* x_in   = (const float*)d_in[0];
  const float* c_in   = (const float*)d_in[1];
  const float* relb   = (const float*)d_in[2];
  const float* w_ada  = (const float*)d_in[3];
  const float* b_ada  = (const float*)d_in[4];
  const float* wqkv_s = (const float*)d_in[5];
  const float* bqkv_s = (const float*)d_in[6];
  const float* wproj_s= (const float*)d_in[7];
  const float* bproj_s= (const float*)d_in[8];
  const float* wqkv_t = (const float*)d_in[9];
  const float* bqkv_t = (const float*)d_in[10];
  const float* wproj_t= (const float*)d_in[11];
  const float* bproj_t= (const float*)d_in[12];
  const float* w1     = (const float*)d_in[13];
  const float* b1     = (const float*)d_in[14];
  const float* w2     = (const float*)d_in[15];
  const float* b2     = (const float*)d_in[16];

  float* Xout = (float*)d_out;
  float* attn = (float*)d_out + (size_t)M_ * C_;

  char* ws = (char*)d_ws;
  float* mod    = (float*)ws;
  bf16*  silu_b = (bf16*)(ws + 1769472);
  bf16*  Wb     = (bf16*)(ws + 1867776);
  bf16*  Bbuf   = (bf16*)(ws + 9240576);
  bf16*  Abuf   = (bf16*)(ws + 28114944);

  bf16* wqkv_s_b  = Wb;
  bf16* wproj_s_b = Wb + 442368;
  bf16* wqkv_t_b  = Wb + 589824;
  bf16* wproj_t_b = Wb + 1032192;
  bf16* w1_b      = Wb + 1179648;
  bf16* w2_b      = Wb + 1769472;
  bf16* wada_b    = Wb + 2359296;

  // raise dynamic-LDS cap for the persistent-W kernel instantiations
  {
    auto* f0 = gemm_pw<float, 0>;
    auto* f1 = gemm_pw<bf16, 0>;
    auto* f2 = gemm_pw<float, 2>;
    auto* f3 = gemm_pw<float, 3>;
    auto* f4 = gemm_pw<bf16, 1>;
    hipFuncSetAttribute((const void*)f0, hipFuncAttributeMaxDynamicSharedMemorySize, 131072);
    hipFuncSetAttribute((const void*)f1, hipFuncAttributeMaxDynamicSharedMemorySize, 131072);
    hipFuncSetAttribute((const void*)f2, hipFuncAttributeMaxDynamicSharedMemorySize, 131072);
    hipFuncSetAttribute((const void*)f3, hipFuncAttributeMaxDynamicSharedMemorySize, 131072);
    hipFuncSetAttribute((const void*)f4, hipFuncAttributeMaxDynamicSharedMemorySize, 131072);
  }

  F2BArgs fa;
  fa.src[0] = wqkv_s;  fa.dst[0] = wqkv_s_b;  fa.n4[0] = 110592;
  fa.src[1] = wproj_s; fa.dst[1] = wproj_s_b; fa.n4[1] = 36864;
  fa.src[2] = wqkv_t;  fa.dst[2] = wqkv_t_b;  fa.n4[2] = 110592;
  fa.src[3] = wproj_t; fa.dst[3] = wproj_t_b; fa.n4[3] = 36864;
  fa.src[4] = w1;      fa.dst[4] = w1_b;      fa.n4[4] = 147456;
  fa.src[5] = w2;      fa.dst[5] = w2_b;      fa.n4[5] = 147456;
  fa.src[6] = w_ada;   fa.dst[6] = wada_b;    fa.n4[6] = 331776;
  k_f2b_all<<<dim3(1296, 7), 256, 0, stream>>>(fa);

  // 1. adaLN modulation (M padded to 128; MT=1)
  k_silu<<<128, 384, 0, stream>>>(c_in, silu_b);
  gemm_pw<float, 0><<<27, 256, 131072, stream>>>(
      silu_b, wada_b, b_ada, mod, 1, NINE_C, nullptr, nullptr, 0, 27, 1);

  // 2. spatial: LN+mod -> qkv -> fused attn -> proj+gated resid
  k_ln_mod<<<M_ / 4, 256, 0, stream>>>(x_in, mod, Bbuf, 0, 1);
  gemm_pw<bf16, 0><<<9 * 28, 256, 131072, stream>>>(
      Bbuf, wqkv_s_b, bqkv_s, Abuf, M_ / 128, QKV_, nullptr, nullptr, 0, 9, 28);
  k_attn_fused<<<BT_ * NH_, 256, 0, stream>>>(Abuf, relb, attn, Bbuf);
  gemm_pw<float, 2><<<3 * 85, 256, 131072, stream>>>(
      Bbuf, wproj_s_b, bproj_s, (float*)Xout, M_ / 128, C_, x_in, mod, 2, 3, 85);

  // 3. temporal: gather-LN -> qkv -> attn -> proj + fused scatter resid
  k_ln_mod_t<<<M_ / 4, 256, 0, stream>>>(Xout, mod, Bbuf);
  gemm_pw<bf16, 0><<<9 * 28, 256, 131072, stream>>>(
      Bbuf, wqkv_t_b, bqkv_t, Abuf, M_ / 128, QKV_, nullptr, nullptr, 0, 9, 28);
  k_attn_t<<<B_ * N_ * NH_, 64, 0, stream>>>(Abuf, Bbuf);
  gemm_pw<float, 3><<<3 * 85, 256, 131072, stream>>>(
      Bbuf, wproj_t_b, bproj_t, (float*)Xout, M_ / 128, C_, nullptr, mod, 5, 3, 85);

  // 4. MLP: LN+mod -> GEMM+GELU -> GEMM + fused gated resid (in-place)
  k_ln_mod<<<M_ / 4, 256, 0, stream>>>(Xout, mod, Bbuf, 6, 7);
  gemm_pw<bf16, 1><<<12 * 21, 256, 131072, stream>>>(
      Bbuf, w1_b, b1, Abuf, M_ / 128, MLP_, nullptr, nullptr, 0, 12, 21);
  mfma_gemm<float, 2><<<(C_/128)*(M_/128), 256, 0, stream>>>(
      Abuf, w2_b, b2, (float*)Xout, M_, C_, MLP_, Xout, mod, 8, C_/128);
}

// Round 8
// 504.852 us; speedup vs baseline: 1.1519x; 1.1519x over previous
//
#include <hip/hip_runtime.h>
#include <hip/hip_bf16.h>
#include <math.h>

typedef __bf16 bf16;
typedef __bf16 bf16x8 __attribute__((ext_vector_type(8)));
typedef __bf16 bf16x4 __attribute__((ext_vector_type(4)));
typedef float  f32x4  __attribute__((ext_vector_type(4)));

#define C_    384
#define NH_   12
#define HD_   32
#define MLP_  1536
#define B_    8
#define T_    12
#define N_    256
#define BT_   96
#define M_    24576
#define NINE_C 3456
#define QKV_  1152

#define GLOAD16(gptr, lptr)                                                \
  __builtin_amdgcn_global_load_lds(                                       \
      (const __attribute__((address_space(1))) void*)(gptr),              \
      (__attribute__((address_space(3))) void*)(lptr), 16, 0, 0)

__device__ __forceinline__ float wave_sum(float v) {
#pragma unroll
  for (int o = 32; o > 0; o >>= 1) v += __shfl_xor(v, o, 64);
  return v;
}

template <typename TO> __device__ __forceinline__ TO to_out(float v);
template <> __device__ __forceinline__ float to_out<float>(float v) { return v; }
template <> __device__ __forceinline__ bf16  to_out<bf16>(float v)  { return (bf16)v; }

// ---------- all f32 -> bf16 weight conversions in one kernel ----------
struct F2BArgs {
  const float* src[7];
  bf16* dst[7];
  int n4[7];
};
__global__ __launch_bounds__(256) void k_f2b_all(F2BArgs a) {
  const int seg = blockIdx.y;
  const int i = blockIdx.x * 256 + threadIdx.x;
  if (i < a.n4[seg]) {
    float4 v = ((const float4*)a.src[seg])[i];
    bf16x4 o;
    o[0] = (bf16)v.x; o[1] = (bf16)v.y; o[2] = (bf16)v.z; o[3] = (bf16)v.w;
    ((bf16x4*)a.dst[seg])[i] = o;
  }
}

// ---------- silu(c) -> bf16, padded to 128 rows ----------
__global__ __launch_bounds__(384) void k_silu(const float* __restrict__ c,
                                              bf16* __restrict__ out) {
  const int row = blockIdx.x, tid = threadIdx.x;
  float v = 0.f;
  if (row < BT_) {
    float cv = c[row * C_ + tid];
    v = cv / (1.f + __expf(-cv));
  }
  out[row * C_ + tid] = (bf16)v;
}

// ---------- LayerNorm + adaLN modulate -> bf16 ----------
__global__ __launch_bounds__(256) void k_ln_mod(const float* __restrict__ x,
                                                const float* __restrict__ mod,
                                                bf16* __restrict__ out,
                                                int shift_chunk, int scale_chunk) {
  const int wave = threadIdx.x >> 6, lane = threadIdx.x & 63;
  const int r = blockIdx.x * 4 + wave;
  const float* xr = x + (size_t)r * C_;
  float v[6];
  float s = 0.f, ss = 0.f;
#pragma unroll
  for (int e = 0; e < 6; ++e) { v[e] = xr[lane + 64 * e]; s += v[e]; ss += v[e] * v[e]; }
  s = wave_sum(s); ss = wave_sum(ss);
  const float mean = s * (1.f / C_);
  const float var  = ss * (1.f / C_) - mean * mean;
  const float rs   = rsqrtf(var + 1e-6f);
  const int bt = r >> 8;
  const float* sh = mod + (size_t)bt * NINE_C + shift_chunk * C_;
  const float* sc = mod + (size_t)bt * NINE_C + scale_chunk * C_;
  bf16* orow = out + (size_t)r * C_;
#pragma unroll
  for (int e = 0; e < 6; ++e) {
    int cc = lane + 64 * e;
    orow[cc] = (bf16)((v[e] - mean) * rs * (1.f + sc[cc]) + sh[cc]);
  }
}

// ---------- temporal LN + modulate (gather) -> bf16 ----------
__global__ __launch_bounds__(256) void k_ln_mod_t(const float* __restrict__ x,
                                                  const float* __restrict__ mod,
                                                  bf16* __restrict__ out) {
  const int wave = threadIdx.x >> 6, lane = threadIdx.x & 63;
  const int rr = blockIdx.x * 4 + wave;          // rr = bn*12 + t
  const int bn = rr / T_, t = rr - bn * T_;
  const int b = bn >> 8, n = bn & 255;
  const int in_row = (b * T_ + t) * N_ + n;
  const int mrow   = b * T_ + t;
  const float* xr = x + (size_t)in_row * C_;
  float v[6];
  float s = 0.f, ss = 0.f;
#pragma unroll
  for (int e = 0; e < 6; ++e) { v[e] = xr[lane + 64 * e]; s += v[e]; ss += v[e] * v[e]; }
  s = wave_sum(s); ss = wave_sum(ss);
  const float mean = s * (1.f / C_);
  const float var  = ss * (1.f / C_) - mean * mean;
  const float rs   = rsqrtf(var + 1e-6f);
  const float* sh = mod + (size_t)mrow * NINE_C + 3 * C_;
  const float* sc = mod + (size_t)mrow * NINE_C + 4 * C_;
  bf16* orow = out + (size_t)rr * C_;
#pragma unroll
  for (int e = 0; e < 6; ++e) {
    int cc = lane + 64 * e;
    orow[cc] = (bf16)((v[e] - mean) * rs * (1.f + sc[cc]) + sh[cc]);
  }
}

// ---------- MFMA GEMM, global_load_lds staging + XCD swizzle (R6, 526us) ----------
template <typename TO, int EPI>
__global__ __launch_bounds__(256) void mfma_gemm(const bf16* __restrict__ A,
                                                 const bf16* __restrict__ W,
                                                 const float* __restrict__ bias,
                                                 TO* __restrict__ out,
                                                 int M, int N, int K,
                                                 const float* __restrict__ base,
                                                 const float* __restrict__ mod,
                                                 int gc, int ntx) {
  __shared__ bf16 As[128 * 64];
  __shared__ bf16 Bs[128 * 64];
  const int tid = threadIdx.x;
  const int w = tid >> 6, l = tid & 63;
  const int nwg = gridDim.x;
  const int q8 = nwg >> 3, r8 = nwg & 7;
  const int xcd = blockIdx.x & 7, idx = blockIdx.x >> 3;
  const int t = (xcd < r8 ? xcd * (q8 + 1) : r8 * (q8 + 1) + (xcd - r8) * q8) + idx;
  const int m0 = (t / ntx) * 128, n0 = (t % ntx) * 128;
  const int wr = w >> 1, wc = w & 1;
  f32x4 acc[4][4];
#pragma unroll
  for (int mi = 0; mi < 4; ++mi)
#pragma unroll
    for (int nj = 0; nj < 4; ++nj) acc[mi][nj] = (f32x4){0.f, 0.f, 0.f, 0.f};

  const int srow8 = l >> 3;
  const int c8    = l & 7;

  for (int k0 = 0; k0 < K; k0 += 64) {
#pragma unroll
    for (int i = 0; i < 4; ++i) {
      int row = w * 32 + i * 8 + srow8;
      int sc = c8 ^ (row & 7);
      GLOAD16(A + (size_t)(m0 + row) * K + k0 + sc * 8,
              (char*)As + (w * 32 + i * 8) * 128);
      GLOAD16(W + (size_t)(n0 + row) * K + k0 + sc * 8,
              (char*)Bs + (w * 32 + i * 8) * 128);
    }
    __syncthreads();
#pragma unroll
    for (int kt = 0; kt < 2; ++kt) {
      bf16x8 a[4], b[4];
      const int cc = kt * 4 + (l >> 4);
#pragma unroll
      for (int mi = 0; mi < 4; ++mi) {
        int row = wr * 64 + mi * 16 + (l & 15);
        a[mi] = *(const bf16x8*)((const char*)As + row * 128 + ((cc ^ (row & 7)) << 4));
      }
#pragma unroll
      for (int nj = 0; nj < 4; ++nj) {
        int row = wc * 64 + nj * 16 + (l & 15);
        b[nj] = *(const bf16x8*)((const char*)Bs + row * 128 + ((cc ^ (row & 7)) << 4));
      }
#pragma unroll
      for (int mi = 0; mi < 4; ++mi)
#pragma unroll
        for (int nj = 0; nj < 4; ++nj)
          acc[mi][nj] = __builtin_amdgcn_mfma_f32_16x16x32_bf16(a[mi], b[nj], acc[mi][nj], 0, 0, 0);
    }
    __syncthreads();
  }
  const int btc = m0 >> 8;
#pragma unroll
  for (int nj = 0; nj < 4; ++nj) {
    int col = n0 + wc * 64 + nj * 16 + (l & 15);
    float bv = bias[col];
    float gv = 0.f;
    if (EPI == 2) gv = mod[(size_t)btc * NINE_C + gc * C_ + col];
#pragma unroll
    for (int mi = 0; mi < 4; ++mi) {
#pragma unroll
      for (int q = 0; q < 4; ++q) {
        int rrow = m0 + wr * 64 + mi * 16 + (l >> 4) * 4 + q;
        float v = acc[mi][nj][q] + bv;
        if (EPI == 0) {
          out[(size_t)rrow * N + col] = to_out<TO>(v);
        } else if (EPI == 1) {
          v = 0.5f * v * (1.f + erff(v * 0.70710678118654752f));
          out[(size_t)rrow * N + col] = to_out<TO>(v);
        } else if (EPI == 2) {
          ((float*)out)[(size_t)rrow * N + col] =
              base[(size_t)rrow * N + col] + gv * v;
        } else {
          int b = rrow / 3072;
          int rem = rrow - b * 3072;
          int n = rem / 12, tt = rem - n * 12;
          int btd = b * 12 + tt;
          size_t dst = ((size_t)btd * 256 + n) * N + col;
          float g = mod[(size_t)btd * NINE_C + 5 * C_ + col];
          ((float*)out)[dst] += g * v;
        }
      }
    }
  }
}

// ---------- fused spatial attention, swapped-QK^T P-row-per-lane layout ----------
// mfma(K_frag, Q_frag): lane (ln,kg) holds S[row=i0+ln][cols nj*16+kg*4+{0..3}].
// Softmax reduce = 2 shuffles (kg lanes). P f32 store = float4 (64B segments).
// PV from bf16 LDS tile (unchanged verified layout).
__global__ __launch_bounds__(256) void k_attn_fused(const bf16* __restrict__ qkv,
                                                    const float* __restrict__ bias,
                                                    float* __restrict__ attn,
                                                    bf16* __restrict__ out) {
  __shared__ bf16 Vt[32 * 256];        // [d][k], rows 512B, XOR-swizzled 16B chunks
  __shared__ bf16 Pl[4][16][260];      // per-wave P tile [row][col], rows 520B
  const int blk = blockIdx.x;
  const int bt = blk / NH_, h = blk - bt * NH_;
  const int tid = threadIdx.x;
#pragma unroll
  for (int r = 0; r < 4; ++r) {
    int id = tid + 256 * r;
    int j = id >> 2, c = id & 3;
    bf16x8 vv = *(const bf16x8*)(qkv + (size_t)(bt * N_ + j) * QKV_ + 2 * C_ + h * HD_ + c * 8);
    int kc = j >> 3, ke = j & 7;
#pragma unroll
    for (int i = 0; i < 8; ++i) {
      int d = c * 8 + i;
      *(bf16*)((char*)Vt + d * 512 + ((kc ^ (d & 7)) << 4) + ke * 2) = vv[i];
    }
  }
  const int w = tid >> 6, l = tid & 63;
  const int ln = l & 15, kg = l >> 4;
  const bf16* kbase = qkv + (size_t)bt * N_ * QKV_ + C_ + h * HD_ + kg * 8;
  bf16x8 kfr[16];
#pragma unroll
  for (int nj = 0; nj < 16; ++nj)
    kfr[nj] = *(const bf16x8*)(kbase + (size_t)(nj * 16 + ln) * QKV_);
  __syncthreads();

  const float scale = 0.17677669529663687f;
  const float* bb = bias + (size_t)h * N_ * N_;
  float* Pb = attn + (size_t)blk * N_ * N_;
  const bf16* qbase = qkv + (size_t)bt * N_ * QKV_ + h * HD_ + kg * 8;
  char* Pw = (char*)&Pl[w][0][0];

  for (int g = 0; g < 4; ++g) {
    const int i0 = w * 64 + g * 16;
    const int row = i0 + ln;                // this lane's P row
    bf16x8 aq = *(const bf16x8*)(qbase + (size_t)row * QKV_);
    f32x4 s[16];
#pragma unroll
    for (int nj = 0; nj < 16; ++nj)        // SWAPPED operands: col <- Q row
      s[nj] = __builtin_amdgcn_mfma_f32_16x16x32_bf16(kfr[nj], aq, (f32x4){0.f,0.f,0.f,0.f}, 0, 0, 0);
    // lane holds S[row][nj*16 + kg*4 + r]
    const float* brow = bb + (size_t)row * N_ + kg * 4;
    float v[16][4];
    float mx = -1e30f;
#pragma unroll
    for (int nj = 0; nj < 16; ++nj) {
      float4 bv = *(const float4*)(brow + nj * 16);
      v[nj][0] = s[nj][0] * scale + bv.x;
      v[nj][1] = s[nj][1] * scale + bv.y;
      v[nj][2] = s[nj][2] * scale + bv.z;
      v[nj][3] = s[nj][3] * scale + bv.w;
      mx = fmaxf(mx, fmaxf(fmaxf(v[nj][0], v[nj][1]), fmaxf(v[nj][2], v[nj][3])));
    }
    mx = fmaxf(mx, __shfl_xor(mx, 16, 64));
    mx = fmaxf(mx, __shfl_xor(mx, 32, 64));
    float sum = 0.f;
#pragma unroll
    for (int nj = 0; nj < 16; ++nj) {
      v[nj][0] = __expf(v[nj][0] - mx);
      v[nj][1] = __expf(v[nj][1] - mx);
      v[nj][2] = __expf(v[nj][2] - mx);
      v[nj][3] = __expf(v[nj][3] - mx);
      sum += (v[nj][0] + v[nj][1]) + (v[nj][2] + v[nj][3]);
    }
    sum += __shfl_xor(sum, 16, 64);
    sum += __shfl_xor(sum, 32, 64);
    const float inv = __frcp_rn(sum);
    float* prow = Pb + (size_t)row * N_ + kg * 4;
#pragma unroll
    for (int nj = 0; nj < 16; ++nj) {
      float4 o;
      o.x = v[nj][0] * inv; o.y = v[nj][1] * inv;
      o.z = v[nj][2] * inv; o.w = v[nj][3] * inv;
      *(float4*)(prow + nj * 16) = o;                       // 64B-coalesced output
      bf16x4 pb;
      pb[0] = (bf16)o.x; pb[1] = (bf16)o.y; pb[2] = (bf16)o.z; pb[3] = (bf16)o.w;
      *(bf16x4*)(Pw + ln * 520 + (nj * 16 + kg * 4) * 2) = pb;  // LDS for PV
    }
    // PV from LDS: A-frag = P[i0+ln][kt*32 + kg*8 .. +7]
    f32x4 o0 = (f32x4){0.f,0.f,0.f,0.f}, o1 = (f32x4){0.f,0.f,0.f,0.f};
#pragma unroll
    for (int kt = 0; kt < 8; ++kt) {
      bf16x8 a = *(const bf16x8*)(Pw + ln * 520 + kt * 64 + kg * 16);
      int kc = kt * 4 + kg;
      bf16x8 b0 = *(const bf16x8*)((const char*)Vt + (size_t)ln * 512 + ((kc ^ (ln & 7)) << 4));
      bf16x8 b1 = *(const bf16x8*)((const char*)Vt + (size_t)(16 + ln) * 512 + ((kc ^ (ln & 7)) << 4));
      o0 = __builtin_amdgcn_mfma_f32_16x16x32_bf16(a, b0, o0, 0, 0, 0);
      o1 = __builtin_amdgcn_mfma_f32_16x16x32_bf16(a, b1, o1, 0, 0, 0);
    }
#pragma unroll
    for (int q = 0; q < 4; ++q) {
      int orow_i = i0 + kg * 4 + q;
      bf16* orow = out + (size_t)(bt * N_ + orow_i) * C_ + h * HD_;
      orow[ln]      = (bf16)o0[q];
      orow[16 + ln] = (bf16)o1[q];
    }
  }
}

// ---------- temporal attention (T=12) -> bf16 ----------
__global__ __launch_bounds__(64) void k_attn_t(const bf16* __restrict__ qkv,
                                               bf16* __restrict__ out) {
  __shared__ float q[T_][HD_], k[T_][HD_], v[T_][HD_];
  const int blk = blockIdx.x;
  const int bn = blk / NH_, h = blk - bn * NH_;
  const int tid = threadIdx.x;
  for (int idx = tid; idx < T_ * 3 * HD_; idx += 64) {
    int t = idx / 96, rem = idx - t * 96;
    int s = rem >> 5, d = rem & 31;
    float val = (float)qkv[(size_t)(bn * T_ + t) * QKV_ + s * C_ + h * HD_ + d];
    if (s == 0) q[t][d] = val;
    else if (s == 1) k[t][d] = val;
    else v[t][d] = val;
  }
  __syncthreads();
  if (tid < T_) {
    const int i = tid;
    float sv[T_];
    float m = -1e30f;
#pragma unroll
    for (int j = 0; j < T_; ++j) {
      float s = 0.f;
#pragma unroll
      for (int d = 0; d < HD_; ++d) s += q[i][d] * k[j][d];
      s *= 0.17677669529663687f;
      sv[j] = s; m = fmaxf(m, s);
    }
    float l = 0.f;
#pragma unroll
    for (int j = 0; j < T_; ++j) { sv[j] = __expf(sv[j] - m); l += sv[j]; }
    const float inv = 1.f / l;
    float o[HD_];
#pragma unroll
    for (int d = 0; d < HD_; ++d) o[d] = 0.f;
#pragma unroll
    for (int j = 0; j < T_; ++j)
#pragma unroll
      for (int d = 0; d < HD_; ++d) o[d] += sv[j] * v[j][d];
    bf16* orow = out + (size_t)(bn * T_ + i) * C_ + h * HD_;
#pragma unroll
    for (int d = 0; d < HD_; ++d) orow[d] = (bf16)(o[d] * inv);
  }
}

extern "C" void kernel_launch(void* const* d_in, const int* in_sizes, int n_in,
                              void* d_out, int out_size, void* d_ws, size_t ws_size,
                              hipStream_t stream) {
  const float* x_in   = (const float*)d_in[0];
  const float* c_in   = (const float*)d_in[1];
  const float* relb   = (const float*)d_in[2];
  const float* w_ada  = (const float*)d_in[3];
  const float* b_ada  = (const float*)d_in[4];
  const float* wqkv_s = (const float*)d_in[5];
  const float* bqkv_s = (const float*)d_in[6];
  const float* wproj_s= (const float*)d_in[7];
  const float* bproj_s= (const float*)d_in[8];
  const float* wqkv_t = (const float*)d_in[9];
  const float* bqkv_t = (const float*)d_in[10];
  const float* wproj_t= (const float*)d_in[11];
  const float* bproj_t= (const float*)d_in[12];
  const float* w1     = (const float*)d_in[13];
  const float* b1     = (const float*)d_in[14];
  const float* w2     = (const float*)d_in[15];
  const float* b2     = (const float*)d_in[16];

  float* Xout = (float*)d_out;
  float* attn = (float*)d_out + (size_t)M_ * C_;

  char* ws = (char*)d_ws;
  float* mod    = (float*)ws;
  bf16*  silu_b = (bf16*)(ws + 1769472);
  bf16*  Wb     = (bf16*)(ws + 1867776);
  bf16*  Bbuf   = (bf16*)(ws + 9240576);
  bf16*  Abuf   = (bf16*)(ws + 28114944);

  bf16* wqkv_s_b  = Wb;
  bf16* wproj_s_b = Wb + 442368;
  bf16* wqkv_t_b  = Wb + 589824;
  bf16* wproj_t_b = Wb + 1032192;
  bf16* w1_b      = Wb + 1179648;
  bf16* w2_b      = Wb + 1769472;
  bf16* wada_b    = Wb + 2359296;

  F2BArgs fa;
  fa.src[0] = wqkv_s;  fa.dst[0] = wqkv_s_b;  fa.n4[0] = 110592;
  fa.src[1] = wproj_s; fa.dst[1] = wproj_s_b; fa.n4[1] = 36864;
  fa.src[2] = wqkv_t;  fa.dst[2] = wqkv_t_b;  fa.n4[2] = 110592;
  fa.src[3] = wproj_t; fa.dst[3] = wproj_t_b; fa.n4[3] = 36864;
  fa.src[4] = w1;      fa.dst[4] = w1_b;      fa.n4[4] = 147456;
  fa.src[5] = w2;      fa.dst[5] = w2_b;      fa.n4[5] = 147456;
  fa.src[6] = w_ada;   fa.dst[6] = wada_b;    fa.n4[6] = 331776;
  k_f2b_all<<<dim3(1296, 7), 256, 0, stream>>>(fa);

  // 1. adaLN modulation via MFMA GEMM (M padded to 128)
  k_silu<<<128, 384, 0, stream>>>(c_in, silu_b);
  mfma_gemm<float, 0><<<27, 256, 0, stream>>>(
      silu_b, wada_b, b_ada, mod, 128, NINE_C, C_, nullptr, nullptr, 0, 27);

  // 2. spatial: LN+mod -> qkv -> fused attn -> proj+gated resid
  k_ln_mod<<<M_ / 4, 256, 0, stream>>>(x_in, mod, Bbuf, 0, 1);
  mfma_gemm<bf16, 0><<<(QKV_/128)*(M_/128), 256, 0, stream>>>(
      Bbuf, wqkv_s_b, bqkv_s, Abuf, M_, QKV_, C_, nullptr, nullptr, 0, QKV_/128);
  k_attn_fused<<<BT_ * NH_, 256, 0, stream>>>(Abuf, relb, attn, Bbuf);
  mfma_gemm<float, 2><<<(C_/128)*(M_/128), 256, 0, stream>>>(
      Bbuf, wproj_s_b, bproj_s, (float*)Xout, M_, C_, C_, x_in, mod, 2, C_/128);

  // 3. temporal: gather-LN -> qkv -> attn -> proj + fused scatter resid
  k_ln_mod_t<<<M_ / 4, 256, 0, stream>>>(Xout, mod, Bbuf);
  mfma_gemm<bf16, 0><<<(QKV_/128)*(M_/128), 256, 0, stream>>>(
      Bbuf, wqkv_t_b, bqkv_t, Abuf, M_, QKV_, C_, nullptr, nullptr, 0, QKV_/128);
  k_attn_t<<<B_ * N_ * NH_, 64, 0, stream>>>(Abuf, Bbuf);
  mfma_gemm<float, 3><<<(C_/128)*(M_/128), 256, 0, stream>>>(
      Bbuf, wproj_t_b, bproj_t, (float*)Xout, M_, C_, C_, nullptr, mod, 5, C_/128);

  // 4. MLP: LN+mod -> GEMM+GELU -> GEMM + fused gated resid (in-place)
  k_ln_mod<<<M_ / 4, 256, 0, stream>>>(Xout, mod, Bbuf, 6, 7);
  mfma_gemm<bf16, 1><<<(MLP_/128)*(M_/128), 256, 0, stream>>>(
      Bbuf, w1_b, b1, Abuf, M_, MLP_, C_, nullptr, nullptr, 0, MLP_/128);
  mfma_gemm<float, 2><<<(C_/128)*(M_/128), 256, 0, stream>>>(
      Abuf, w2_b, b2, (float*)Xout, M_, C_, MLP_, Xout, mod, 8, C_/128);
}

// Round 10
// 446.190 us; speedup vs baseline: 1.3034x; 1.1315x over previous
//
#include <hip/hip_runtime.h>
#include <hip/hip_bf16.h>
#include <math.h>

typedef __bf16 bf16;
typedef __bf16 bf16x8 __attribute__((ext_vector_type(8)));
typedef __bf16 bf16x4 __attribute__((ext_vector_type(4)));
typedef float  f32x4  __attribute__((ext_vector_type(4)));

#define C_    384
#define NH_   12
#define HD_   32
#define MLP_  1536
#define B_    8
#define T_    12
#define N_    256
#define BT_   96
#define M_    24576
#define NINE_C 3456
#define QKV_  1152

#define GLOAD16(gptr, lptr)                                                \
  __builtin_amdgcn_global_load_lds(                                       \
      (const __attribute__((address_space(1))) void*)(gptr),              \
      (__attribute__((address_space(3))) void*)(lptr), 16, 0, 0)

__device__ __forceinline__ float wave_sum(float v) {
#pragma unroll
  for (int o = 32; o > 0; o >>= 1) v += __shfl_xor(v, o, 64);
  return v;
}

template <typename TO> __device__ __forceinline__ TO to_out(float v);
template <> __device__ __forceinline__ float to_out<float>(float v) { return v; }
template <> __device__ __forceinline__ bf16  to_out<bf16>(float v)  { return (bf16)v; }

// ---------- f32->bf16 weight conversions + silu(c) pad, one kernel ----------
struct F2BArgs {
  const float* src[8];
  bf16* dst[8];
  int n4[8];
};
__global__ __launch_bounds__(256) void k_f2b_all(F2BArgs a) {
  const int seg = blockIdx.y;
  const int i = blockIdx.x * 256 + threadIdx.x;
  if (i >= a.n4[seg]) return;
  if (seg == 7) {
    // silu(c) padded to 128 rows (quads 9216..12287 are zero rows 96..127)
    bf16x4 o;
    if (i < 9216) {
      float4 v = ((const float4*)a.src[7])[i];
      o[0] = (bf16)(v.x / (1.f + __expf(-v.x)));
      o[1] = (bf16)(v.y / (1.f + __expf(-v.y)));
      o[2] = (bf16)(v.z / (1.f + __expf(-v.z)));
      o[3] = (bf16)(v.w / (1.f + __expf(-v.w)));
    } else {
      o[0] = o[1] = o[2] = o[3] = (bf16)0.f;
    }
    ((bf16x4*)a.dst[7])[i] = o;
    return;
  }
  float4 v = ((const float4*)a.src[seg])[i];
  bf16x4 o;
  o[0] = (bf16)v.x; o[1] = (bf16)v.y; o[2] = (bf16)v.z; o[3] = (bf16)v.w;
  ((bf16x4*)a.dst[seg])[i] = o;
}

// ---------- LayerNorm + adaLN modulate -> bf16 (float2-vectorized) ----------
__global__ __launch_bounds__(256) void k_ln_mod(const float* __restrict__ x,
                                                const float* __restrict__ mod,
                                                bf16* __restrict__ out,
                                                int shift_chunk, int scale_chunk) {
  const int wave = threadIdx.x >> 6, lane = threadIdx.x & 63;
  const int r = blockIdx.x * 4 + wave;
  const float* xr = x + (size_t)r * C_;
  float2 v[3];
  float s = 0.f, ss = 0.f;
#pragma unroll
  for (int e = 0; e < 3; ++e) {
    v[e] = *(const float2*)&xr[lane * 2 + 128 * e];
    s += v[e].x + v[e].y;
    ss += v[e].x * v[e].x + v[e].y * v[e].y;
  }
  s = wave_sum(s); ss = wave_sum(ss);
  const float mean = s * (1.f / C_);
  const float var  = ss * (1.f / C_) - mean * mean;
  const float rs   = rsqrtf(var + 1e-6f);
  const int bt = r >> 8;
  const float* sh = mod + (size_t)bt * NINE_C + shift_chunk * C_;
  const float* sc = mod + (size_t)bt * NINE_C + scale_chunk * C_;
  bf16* orow = out + (size_t)r * C_;
#pragma unroll
  for (int e = 0; e < 3; ++e) {
    int cc = lane * 2 + 128 * e;
    float2 s2 = *(const float2*)&sc[cc];
    float2 h2 = *(const float2*)&sh[cc];
    union { bf16 b[2]; unsigned u; } pk;
    pk.b[0] = (bf16)((v[e].x - mean) * rs * (1.f + s2.x) + h2.x);
    pk.b[1] = (bf16)((v[e].y - mean) * rs * (1.f + s2.y) + h2.y);
    *(unsigned*)&orow[cc] = pk.u;
  }
}

// ---------- MFMA GEMM, global_load_lds staging + XCD swizzle ----------
// EPI 0 plain / 1 exact GELU / 2 gated residual / 4 gated residual w/ NT store.
template <typename TO, int EPI>
__global__ __launch_bounds__(256) void mfma_gemm(const bf16* __restrict__ A,
                                                 const bf16* __restrict__ W,
                                                 const float* __restrict__ bias,
                                                 TO* __restrict__ out,
                                                 int M, int N, int K,
                                                 const float* __restrict__ base,
                                                 const float* __restrict__ mod,
                                                 int gc, int ntx) {
  __shared__ bf16 As[128 * 64];
  __shared__ bf16 Bs[128 * 64];
  const int tid = threadIdx.x;
  const int w = tid >> 6, l = tid & 63;
  const int nwg = gridDim.x;
  const int q8 = nwg >> 3, r8 = nwg & 7;
  const int xcd = blockIdx.x & 7, idx = blockIdx.x >> 3;
  const int t = (xcd < r8 ? xcd * (q8 + 1) : r8 * (q8 + 1) + (xcd - r8) * q8) + idx;
  const int m0 = (t / ntx) * 128, n0 = (t % ntx) * 128;
  const int wr = w >> 1, wc = w & 1;
  f32x4 acc[4][4];
#pragma unroll
  for (int mi = 0; mi < 4; ++mi)
#pragma unroll
    for (int nj = 0; nj < 4; ++nj) acc[mi][nj] = (f32x4){0.f, 0.f, 0.f, 0.f};

  const int srow8 = l >> 3;
  const int c8    = l & 7;

  for (int k0 = 0; k0 < K; k0 += 64) {
#pragma unroll
    for (int i = 0; i < 4; ++i) {
      int row = w * 32 + i * 8 + srow8;
      int sc = c8 ^ (row & 7);
      GLOAD16(A + (size_t)(m0 + row) * K + k0 + sc * 8,
              (char*)As + (w * 32 + i * 8) * 128);
      GLOAD16(W + (size_t)(n0 + row) * K + k0 + sc * 8,
              (char*)Bs + (w * 32 + i * 8) * 128);
    }
    __syncthreads();
#pragma unroll
    for (int kt = 0; kt < 2; ++kt) {
      bf16x8 a[4], b[4];
      const int cc = kt * 4 + (l >> 4);
#pragma unroll
      for (int mi = 0; mi < 4; ++mi) {
        int row = wr * 64 + mi * 16 + (l & 15);
        a[mi] = *(const bf16x8*)((const char*)As + row * 128 + ((cc ^ (row & 7)) << 4));
      }
#pragma unroll
      for (int nj = 0; nj < 4; ++nj) {
        int row = wc * 64 + nj * 16 + (l & 15);
        b[nj] = *(const bf16x8*)((const char*)Bs + row * 128 + ((cc ^ (row & 7)) << 4));
      }
#pragma unroll
      for (int mi = 0; mi < 4; ++mi)
#pragma unroll
        for (int nj = 0; nj < 4; ++nj)
          acc[mi][nj] = __builtin_amdgcn_mfma_f32_16x16x32_bf16(a[mi], b[nj], acc[mi][nj], 0, 0, 0);
    }
    __syncthreads();
  }
  const int btc = m0 >> 8;
#pragma unroll
  for (int nj = 0; nj < 4; ++nj) {
    int col = n0 + wc * 64 + nj * 16 + (l & 15);
    float bv = bias[col];
    float gv = 0.f;
    if (EPI == 2 || EPI == 4) gv = mod[(size_t)btc * NINE_C + gc * C_ + col];
#pragma unroll
    for (int mi = 0; mi < 4; ++mi) {
#pragma unroll
      for (int q = 0; q < 4; ++q) {
        int rrow = m0 + wr * 64 + mi * 16 + (l >> 4) * 4 + q;
        float v = acc[mi][nj][q] + bv;
        if (EPI == 0) {
          out[(size_t)rrow * N + col] = to_out<TO>(v);
        } else if (EPI == 1) {
          v = 0.5f * v * (1.f + erff(v * 0.70710678118654752f));
          out[(size_t)rrow * N + col] = to_out<TO>(v);
        } else if (EPI == 2) {
          ((float*)out)[(size_t)rrow * N + col] =
              base[(size_t)rrow * N + col] + gv * v;
        } else {
          float o = base[(size_t)rrow * N + col] + gv * v;
          __builtin_nontemporal_store(o, &((float*)out)[(size_t)rrow * N + col]);
        }
      }
    }
  }
}

// ---------- fused spatial attention, swapped-QK^T P-row-per-lane layout ----------
__global__ __launch_bounds__(256) void k_attn_fused(const bf16* __restrict__ qkv,
                                                    const float* __restrict__ bias,
                                                    float* __restrict__ attn,
                                                    bf16* __restrict__ out) {
  __shared__ bf16 Vt[32 * 256];        // [d][k], rows 512B, XOR-swizzled 16B chunks
  __shared__ bf16 Pl[4][16][260];      // per-wave P tile [row][col], rows 520B
  const int blk = blockIdx.x;
  const int bt = blk / NH_, h = blk - bt * NH_;
  const int tid = threadIdx.x;
#pragma unroll
  for (int r = 0; r < 4; ++r) {
    int id = tid + 256 * r;
    int j = id >> 2, c = id & 3;
    bf16x8 vv = *(const bf16x8*)(qkv + (size_t)(bt * N_ + j) * QKV_ + 2 * C_ + h * HD_ + c * 8);
    int kc = j >> 3, ke = j & 7;
#pragma unroll
    for (int i = 0; i < 8; ++i) {
      int d = c * 8 + i;
      *(bf16*)((char*)Vt + d * 512 + ((kc ^ (d & 7)) << 4) + ke * 2) = vv[i];
    }
  }
  const int w = tid >> 6, l = tid & 63;
  const int ln = l & 15, kg = l >> 4;
  const bf16* kbase = qkv + (size_t)bt * N_ * QKV_ + C_ + h * HD_ + kg * 8;
  bf16x8 kfr[16];
#pragma unroll
  for (int nj = 0; nj < 16; ++nj)
    kfr[nj] = *(const bf16x8*)(kbase + (size_t)(nj * 16 + ln) * QKV_);
  __syncthreads();

  const float scale = 0.17677669529663687f;
  const float* bb = bias + (size_t)h * N_ * N_;
  float* Pb = attn + (size_t)blk * N_ * N_;
  const bf16* qbase = qkv + (size_t)bt * N_ * QKV_ + h * HD_ + kg * 8;
  char* Pw = (char*)&Pl[w][0][0];

  for (int g = 0; g < 4; ++g) {
    const int i0 = w * 64 + g * 16;
    const int row = i0 + ln;                // this lane's P row
    bf16x8 aq = *(const bf16x8*)(qbase + (size_t)row * QKV_);
    f32x4 s[16];
#pragma unroll
    for (int nj = 0; nj < 16; ++nj)        // SWAPPED operands: lane owns a P row
      s[nj] = __builtin_amdgcn_mfma_f32_16x16x32_bf16(kfr[nj], aq, (f32x4){0.f,0.f,0.f,0.f}, 0, 0, 0);
    const float* brow = bb + (size_t)row * N_ + kg * 4;
    float v[16][4];
    float mx = -1e30f;
#pragma unroll
    for (int nj = 0; nj < 16; ++nj) {
      float4 bv = *(const float4*)(brow + nj * 16);
      v[nj][0] = s[nj][0] * scale + bv.x;
      v[nj][1] = s[nj][1] * scale + bv.y;
      v[nj][2] = s[nj][2] * scale + bv.z;
      v[nj][3] = s[nj][3] * scale + bv.w;
      mx = fmaxf(mx, fmaxf(fmaxf(v[nj][0], v[nj][1]), fmaxf(v[nj][2], v[nj][3])));
    }
    mx = fmaxf(mx, __shfl_xor(mx, 16, 64));
    mx = fmaxf(mx, __shfl_xor(mx, 32, 64));
    float sum = 0.f;
#pragma unroll
    for (int nj = 0; nj < 16; ++nj) {
      v[nj][0] = __expf(v[nj][0] - mx);
      v[nj][1] = __expf(v[nj][1] - mx);
      v[nj][2] = __expf(v[nj][2] - mx);
      v[nj][3] = __expf(v[nj][3] - mx);
      sum += (v[nj][0] + v[nj][1]) + (v[nj][2] + v[nj][3]);
    }
    sum += __shfl_xor(sum, 16, 64);
    sum += __shfl_xor(sum, 32, 64);
    const float inv = __frcp_rn(sum);
    float* prow = Pb + (size_t)row * N_ + kg * 4;
#pragma unroll
    for (int nj = 0; nj < 16; ++nj) {
      f32x4 o;
      o[0] = v[nj][0] * inv; o[1] = v[nj][1] * inv;
      o[2] = v[nj][2] * inv; o[3] = v[nj][3] * inv;
      __builtin_nontemporal_store(o, (f32x4*)(prow + nj * 16)); // never re-read
      bf16x4 pb;
      pb[0] = (bf16)o[0]; pb[1] = (bf16)o[1]; pb[2] = (bf16)o[2]; pb[3] = (bf16)o[3];
      *(bf16x4*)(Pw + ln * 520 + (nj * 16 + kg * 4) * 2) = pb;  // LDS for PV
    }
    // PV from LDS: A-frag = P[i0+ln][kt*32 + kg*8 .. +7]
    f32x4 o0 = (f32x4){0.f,0.f,0.f,0.f}, o1 = (f32x4){0.f,0.f,0.f,0.f};
#pragma unroll
    for (int kt = 0; kt < 8; ++kt) {
      bf16x8 a = *(const bf16x8*)(Pw + ln * 520 + kt * 64 + kg * 16);
      int kc = kt * 4 + kg;
      bf16x8 b0 = *(const bf16x8*)((const char*)Vt + (size_t)ln * 512 + ((kc ^ (ln & 7)) << 4));
      bf16x8 b1 = *(const bf16x8*)((const char*)Vt + (size_t)(16 + ln) * 512 + ((kc ^ (ln & 7)) << 4));
      o0 = __builtin_amdgcn_mfma_f32_16x16x32_bf16(a, b0, o0, 0, 0, 0);
      o1 = __builtin_amdgcn_mfma_f32_16x16x32_bf16(a, b1, o1, 0, 0, 0);
    }
#pragma unroll
    for (int q = 0; q < 4; ++q) {
      int orow_i = i0 + kg * 4 + q;
      bf16* orow = out + (size_t)(bt * N_ + orow_i) * C_ + h * HD_;
      orow[ln]      = (bf16)o0[q];
      orow[16 + ln] = (bf16)o1[q];
    }
  }
}

// ---------- temporal attention (T=12), gathered rows in (bt,n) layout ----------
__global__ __launch_bounds__(64) void k_attn_t(const bf16* __restrict__ qkv,
                                               bf16* __restrict__ out) {
  __shared__ float q[T_][HD_], k[T_][HD_], v[T_][HD_];
  const int blk = blockIdx.x;
  const int bn = blk / NH_, h = blk - bn * NH_;
  const int b = bn >> 8, n = bn & 255;
  const int tid = threadIdx.x;
  for (int idx = tid; idx < T_ * 3 * HD_; idx += 64) {
    int t = idx / 96, rem = idx - t * 96;
    int s = rem >> 5, d = rem & 31;
    const int row = (b * T_ + t) * N_ + n;
    float val = (float)qkv[(size_t)row * QKV_ + s * C_ + h * HD_ + d];
    if (s == 0) q[t][d] = val;
    else if (s == 1) k[t][d] = val;
    else v[t][d] = val;
  }
  __syncthreads();
  if (tid < T_) {
    const int i = tid;
    float sv[T_];
    float m = -1e30f;
#pragma unroll
    for (int j = 0; j < T_; ++j) {
      float s = 0.f;
#pragma unroll
      for (int d = 0; d < HD_; ++d) s += q[i][d] * k[j][d];
      s *= 0.17677669529663687f;
      sv[j] = s; m = fmaxf(m, s);
    }
    float l = 0.f;
#pragma unroll
    for (int j = 0; j < T_; ++j) { sv[j] = __expf(sv[j] - m); l += sv[j]; }
    const float inv = 1.f / l;
    float o[HD_];
#pragma unroll
    for (int d = 0; d < HD_; ++d) o[d] = 0.f;
#pragma unroll
    for (int j = 0; j < T_; ++j)
#pragma unroll
      for (int d = 0; d < HD_; ++d) o[d] += sv[j] * v[j][d];
    bf16* orow = out + (size_t)((b * T_ + i) * N_ + n) * C_ + h * HD_;
#pragma unroll
    for (int d = 0; d < HD_; ++d) orow[d] = (bf16)(o[d] * inv);
  }
}

extern "C" void kernel_launch(void* const* d_in, const int* in_sizes, int n_in,
                              void* d_out, int out_size, void* d_ws, size_t ws_size,
                              hipStream_t stream) {
  const float* x_in   = (const float*)d_in[0];
  const float* c_in   = (const float*)d_in[1];
  const float* relb   = (const float*)d_in[2];
  const float* w_ada  = (const float*)d_in[3];
  const float* b_ada  = (const float*)d_in[4];
  const float* wqkv_s = (const float*)d_in[5];
  const float* bqkv_s = (const float*)d_in[6];
  const float* wproj_s= (const float*)d_in[7];
  const float* bproj_s= (const float*)d_in[8];
  const float* wqkv_t = (const float*)d_in[9];
  const float* bqkv_t = (const float*)d_in[10];
  const float* wproj_t= (const float*)d_in[11];
  const float* bproj_t= (const float*)d_in[12];
  const float* w1     = (const float*)d_in[13];
  const float* b1     = (const float*)d_in[14];
  const float* w2     = (const float*)d_in[15];
  const float* b2     = (const float*)d_in[16];

  float* Xout = (float*)d_out;
  float* attn = (float*)d_out + (size_t)M_ * C_;

  char* ws = (char*)d_ws;
  float* mod    = (float*)ws;
  bf16*  silu_b = (bf16*)(ws + 1769472);
  bf16*  Wb     = (bf16*)(ws + 1867776);
  bf16*  Bbuf   = (bf16*)(ws + 9240576);
  bf16*  Abuf   = (bf16*)(ws + 28114944);

  bf16* wqkv_s_b  = Wb;
  bf16* wproj_s_b = Wb + 442368;
  bf16* wqkv_t_b  = Wb + 589824;
  bf16* wproj_t_b = Wb + 1032192;
  bf16* w1_b      = Wb + 1179648;
  bf16* w2_b      = Wb + 1769472;
  bf16* wada_b    = Wb + 2359296;

  F2BArgs fa;
  fa.src[0] = wqkv_s;  fa.dst[0] = wqkv_s_b;  fa.n4[0] = 110592;
  fa.src[1] = wproj_s; fa.dst[1] = wproj_s_b; fa.n4[1] = 36864;
  fa.src[2] = wqkv_t;  fa.dst[2] = wqkv_t_b;  fa.n4[2] = 110592;
  fa.src[3] = wproj_t; fa.dst[3] = wproj_t_b; fa.n4[3] = 36864;
  fa.src[4] = w1;      fa.dst[4] = w1_b;      fa.n4[4] = 147456;
  fa.src[5] = w2;      fa.dst[5] = w2_b;      fa.n4[5] = 147456;
  fa.src[6] = w_ada;   fa.dst[6] = wada_b;    fa.n4[6] = 331776;
  fa.src[7] = c_in;    fa.dst[7] = silu_b;    fa.n4[7] = 12288;
  k_f2b_all<<<dim3(1296, 8), 256, 0, stream>>>(fa);

  // 1. adaLN modulation via MFMA GEMM (M padded to 128)
  mfma_gemm<float, 0><<<27, 256, 0, stream>>>(
      silu_b, wada_b, b_ada, mod, 128, NINE_C, C_, nullptr, nullptr, 0, 27);

  // 2. spatial: LN+mod -> qkv -> fused attn -> proj + gated resid
  k_ln_mod<<<M_ / 4, 256, 0, stream>>>(x_in, mod, Bbuf, 0, 1);
  mfma_gemm<bf16, 0><<<(QKV_/128)*(M_/128), 256, 0, stream>>>(
      Bbuf, wqkv_s_b, bqkv_s, Abuf, M_, QKV_, C_, nullptr, nullptr, 0, QKV_/128);
  k_attn_fused<<<BT_ * NH_, 256, 0, stream>>>(Abuf, relb, attn, Bbuf);
  mfma_gemm<float, 2><<<(C_/128)*(M_/128), 256, 0, stream>>>(
      Bbuf, wproj_s_b, bproj_s, (float*)Xout, M_, C_, C_, x_in, mod, 2, C_/128);

  // 3. temporal (standard (bt,n) layout; transpose folded into attn_t gather):
  k_ln_mod<<<M_ / 4, 256, 0, stream>>>(Xout, mod, Bbuf, 3, 4);
  mfma_gemm<bf16, 0><<<(QKV_/128)*(M_/128), 256, 0, stream>>>(
      Bbuf, wqkv_t_b, bqkv_t, Abuf, M_, QKV_, C_, nullptr, nullptr, 0, QKV_/128);
  k_attn_t<<<B_ * N_ * NH_, 64, 0, stream>>>(Abuf, Bbuf);
  mfma_gemm<float, 2><<<(C_/128)*(M_/128), 256, 0, stream>>>(
      Bbuf, wproj_t_b, bproj_t, (float*)Xout, M_, C_, C_, Xout, mod, 5, C_/128);

  // 4. MLP: LN+mod -> GEMM+GELU -> GEMM + gated resid (in place, NT final store)
  k_ln_mod<<<M_ / 4, 256, 0, stream>>>(Xout, mod, Bbuf, 6, 7);
  mfma_gemm<bf16, 1><<<(MLP_/128)*(M_/128), 256, 0, stream>>>(
      Bbuf, w1_b, b1, Abuf, M_, MLP_, C_, nullptr, nullptr, 0, MLP_/128);
  mfma_gemm<float, 4><<<(C_/128)*(M_/128), 256, 0, stream>>>(
      Abuf, w2_b, b2, (float*)Xout, M_, C_, MLP_, Xout, mod, 8, C_/128);
}

// Round 11
// 434.859 us; speedup vs baseline: 1.3374x; 1.0261x over previous
//
#include <hip/hip_runtime.h>
#include <hip/hip_bf16.h>
#include <math.h>

typedef __bf16 bf16;
typedef __bf16 bf16x8 __attribute__((ext_vector_type(8)));
typedef __bf16 bf16x4 __attribute__((ext_vector_type(4)));
typedef float  f32x4  __attribute__((ext_vector_type(4)));

#define C_    384
#define NH_   12
#define HD_   32
#define MLP_  1536
#define B_    8
#define T_    12
#define N_    256
#define BT_   96
#define M_    24576
#define NINE_C 3456
#define QKV_  1152

#define GLOAD16(gptr, lptr)                                                \
  __builtin_amdgcn_global_load_lds(                                       \
      (const __attribute__((address_space(1))) void*)(gptr),              \
      (__attribute__((address_space(3))) void*)(lptr), 16, 0, 0)

__device__ __forceinline__ float wave_sum(float v) {
#pragma unroll
  for (int o = 32; o > 0; o >>= 1) v += __shfl_xor(v, o, 64);
  return v;
}

template <typename TO> __device__ __forceinline__ TO to_out(float v);
template <> __device__ __forceinline__ float to_out<float>(float v) { return v; }
template <> __device__ __forceinline__ bf16  to_out<bf16>(float v)  { return (bf16)v; }

// ---------- f32->bf16 weight conversions + silu(c) pad, flat grid ----------
struct F2BArgs {
  const float* src[8];
  bf16* dst[8];
  int n4[8];
  int start[9];   // cumulative block offsets
};
__global__ __launch_bounds__(256) void k_f2b_all(F2BArgs a) {
  const int blk = blockIdx.x;
  int seg = 0;
#pragma unroll
  for (int s = 1; s < 8; ++s) seg += (blk >= a.start[s]);
  const int i = (blk - a.start[seg]) * 256 + threadIdx.x;
  if (i >= a.n4[seg]) return;
  if (seg == 7) {
    bf16x4 o;
    if (i < 9216) {
      float4 v = ((const float4*)a.src[7])[i];
      o[0] = (bf16)(v.x / (1.f + __expf(-v.x)));
      o[1] = (bf16)(v.y / (1.f + __expf(-v.y)));
      o[2] = (bf16)(v.z / (1.f + __expf(-v.z)));
      o[3] = (bf16)(v.w / (1.f + __expf(-v.w)));
    } else {
      o[0] = o[1] = o[2] = o[3] = (bf16)0.f;
    }
    ((bf16x4*)a.dst[7])[i] = o;
    return;
  }
  float4 v = ((const float4*)a.src[seg])[i];
  bf16x4 o;
  o[0] = (bf16)v.x; o[1] = (bf16)v.y; o[2] = (bf16)v.z; o[3] = (bf16)v.w;
  ((bf16x4*)a.dst[seg])[i] = o;
}

// ---------- LayerNorm + adaLN modulate -> bf16 (float2-vectorized) ----------
__global__ __launch_bounds__(256) void k_ln_mod(const float* __restrict__ x,
                                                const float* __restrict__ mod,
                                                bf16* __restrict__ out,
                                                int shift_chunk, int scale_chunk) {
  const int wave = threadIdx.x >> 6, lane = threadIdx.x & 63;
  const int r = blockIdx.x * 4 + wave;
  const float* xr = x + (size_t)r * C_;
  float2 v[3];
  float s = 0.f, ss = 0.f;
#pragma unroll
  for (int e = 0; e < 3; ++e) {
    v[e] = *(const float2*)&xr[lane * 2 + 128 * e];
    s += v[e].x + v[e].y;
    ss += v[e].x * v[e].x + v[e].y * v[e].y;
  }
  s = wave_sum(s); ss = wave_sum(ss);
  const float mean = s * (1.f / C_);
  const float var  = ss * (1.f / C_) - mean * mean;
  const float rs   = rsqrtf(var + 1e-6f);
  const int bt = r >> 8;
  const float* sh = mod + (size_t)bt * NINE_C + shift_chunk * C_;
  const float* sc = mod + (size_t)bt * NINE_C + scale_chunk * C_;
  bf16* orow = out + (size_t)r * C_;
#pragma unroll
  for (int e = 0; e < 3; ++e) {
    int cc = lane * 2 + 128 * e;
    float2 s2 = *(const float2*)&sc[cc];
    float2 h2 = *(const float2*)&sh[cc];
    union { bf16 b[2]; unsigned u; } pk;
    pk.b[0] = (bf16)((v[e].x - mean) * rs * (1.f + s2.x) + h2.x);
    pk.b[1] = (bf16)((v[e].y - mean) * rs * (1.f + s2.y) + h2.y);
    *(unsigned*)&orow[cc] = pk.u;
  }
}

// ---------- MFMA GEMM, global_load_lds staging + XCD swizzle ----------
// EPI 0 plain / 1 exact GELU / 2 gated residual / 4 gated residual w/ NT store.
template <typename TO, int EPI>
__global__ __launch_bounds__(256) void mfma_gemm(const bf16* __restrict__ A,
                                                 const bf16* __restrict__ W,
                                                 const float* __restrict__ bias,
                                                 TO* __restrict__ out,
                                                 int M, int N, int K,
                                                 const float* __restrict__ base,
                                                 const float* __restrict__ mod,
                                                 int gc, int ntx) {
  __shared__ bf16 As[128 * 64];
  __shared__ bf16 Bs[128 * 64];
  const int tid = threadIdx.x;
  const int w = tid >> 6, l = tid & 63;
  const int nwg = gridDim.x;
  const int q8 = nwg >> 3, r8 = nwg & 7;
  const int xcd = blockIdx.x & 7, idx = blockIdx.x >> 3;
  const int t = (xcd < r8 ? xcd * (q8 + 1) : r8 * (q8 + 1) + (xcd - r8) * q8) + idx;
  const int m0 = (t / ntx) * 128, n0 = (t % ntx) * 128;
  const int wr = w >> 1, wc = w & 1;
  f32x4 acc[4][4];
#pragma unroll
  for (int mi = 0; mi < 4; ++mi)
#pragma unroll
    for (int nj = 0; nj < 4; ++nj) acc[mi][nj] = (f32x4){0.f, 0.f, 0.f, 0.f};

  const int srow8 = l >> 3;
  const int c8    = l & 7;

  for (int k0 = 0; k0 < K; k0 += 64) {
#pragma unroll
    for (int i = 0; i < 4; ++i) {
      int row = w * 32 + i * 8 + srow8;
      int sc = c8 ^ (row & 7);
      GLOAD16(A + (size_t)(m0 + row) * K + k0 + sc * 8,
              (char*)As + (w * 32 + i * 8) * 128);
      GLOAD16(W + (size_t)(n0 + row) * K + k0 + sc * 8,
              (char*)Bs + (w * 32 + i * 8) * 128);
    }
    __syncthreads();
#pragma unroll
    for (int kt = 0; kt < 2; ++kt) {
      bf16x8 a[4], b[4];
      const int cc = kt * 4 + (l >> 4);
#pragma unroll
      for (int mi = 0; mi < 4; ++mi) {
        int row = wr * 64 + mi * 16 + (l & 15);
        a[mi] = *(const bf16x8*)((const char*)As + row * 128 + ((cc ^ (row & 7)) << 4));
      }
#pragma unroll
      for (int nj = 0; nj < 4; ++nj) {
        int row = wc * 64 + nj * 16 + (l & 15);
        b[nj] = *(const bf16x8*)((const char*)Bs + row * 128 + ((cc ^ (row & 7)) << 4));
      }
#pragma unroll
      for (int mi = 0; mi < 4; ++mi)
#pragma unroll
        for (int nj = 0; nj < 4; ++nj)
          acc[mi][nj] = __builtin_amdgcn_mfma_f32_16x16x32_bf16(a[mi], b[nj], acc[mi][nj], 0, 0, 0);
    }
    __syncthreads();
  }
  const int btc = m0 >> 8;
#pragma unroll
  for (int nj = 0; nj < 4; ++nj) {
    int col = n0 + wc * 64 + nj * 16 + (l & 15);
    float bv = bias[col];
    float gv = 0.f;
    if (EPI == 2 || EPI == 4) gv = mod[(size_t)btc * NINE_C + gc * C_ + col];
#pragma unroll
    for (int mi = 0; mi < 4; ++mi) {
#pragma unroll
      for (int q = 0; q < 4; ++q) {
        int rrow = m0 + wr * 64 + mi * 16 + (l >> 4) * 4 + q;
        float v = acc[mi][nj][q] + bv;
        if (EPI == 0) {
          out[(size_t)rrow * N + col] = to_out<TO>(v);
        } else if (EPI == 1) {
          v = 0.5f * v * (1.f + erff(v * 0.70710678118654752f));
          out[(size_t)rrow * N + col] = to_out<TO>(v);
        } else if (EPI == 2) {
          ((float*)out)[(size_t)rrow * N + col] =
              base[(size_t)rrow * N + col] + gv * v;
        } else {
          float o = base[(size_t)rrow * N + col] + gv * v;
          __builtin_nontemporal_store(o, &((float*)out)[(size_t)rrow * N + col]);
        }
      }
    }
  }
}

// ---------- fused spatial attention, swapped-QK^T P-row-per-lane layout ----------
__global__ __launch_bounds__(256) void k_attn_fused(const bf16* __restrict__ qkv,
                                                    const float* __restrict__ bias,
                                                    float* __restrict__ attn,
                                                    bf16* __restrict__ out) {
  __shared__ bf16 Vt[32 * 256];        // [d][k], rows 512B, XOR-swizzled 16B chunks
  __shared__ bf16 Pl[4][16][260];      // per-wave P tile [row][col], rows 520B
  const int blk = blockIdx.x;
  const int bt = blk / NH_, h = blk - bt * NH_;
  const int tid = threadIdx.x;
#pragma unroll
  for (int r = 0; r < 4; ++r) {
    int id = tid + 256 * r;
    int j = id >> 2, c = id & 3;
    bf16x8 vv = *(const bf16x8*)(qkv + (size_t)(bt * N_ + j) * QKV_ + 2 * C_ + h * HD_ + c * 8);
    int kc = j >> 3, ke = j & 7;
#pragma unroll
    for (int i = 0; i < 8; ++i) {
      int d = c * 8 + i;
      *(bf16*)((char*)Vt + d * 512 + ((kc ^ (d & 7)) << 4) + ke * 2) = vv[i];
    }
  }
  const int w = tid >> 6, l = tid & 63;
  const int ln = l & 15, kg = l >> 4;
  const bf16* kbase = qkv + (size_t)bt * N_ * QKV_ + C_ + h * HD_ + kg * 8;
  bf16x8 kfr[16];
#pragma unroll
  for (int nj = 0; nj < 16; ++nj)
    kfr[nj] = *(const bf16x8*)(kbase + (size_t)(nj * 16 + ln) * QKV_);
  __syncthreads();

  const float scale = 0.17677669529663687f;
  const float* bb = bias + (size_t)h * N_ * N_;
  float* Pb = attn + (size_t)blk * N_ * N_;
  const bf16* qbase = qkv + (size_t)bt * N_ * QKV_ + h * HD_ + kg * 8;
  char* Pw = (char*)&Pl[w][0][0];

  for (int g = 0; g < 4; ++g) {
    const int i0 = w * 64 + g * 16;
    const int row = i0 + ln;
    bf16x8 aq = *(const bf16x8*)(qbase + (size_t)row * QKV_);
    f32x4 s[16];
#pragma unroll
    for (int nj = 0; nj < 16; ++nj)
      s[nj] = __builtin_amdgcn_mfma_f32_16x16x32_bf16(kfr[nj], aq, (f32x4){0.f,0.f,0.f,0.f}, 0, 0, 0);
    const float* brow = bb + (size_t)row * N_ + kg * 4;
    float v[16][4];
    float mx = -1e30f;
#pragma unroll
    for (int nj = 0; nj < 16; ++nj) {
      float4 bv = *(const float4*)(brow + nj * 16);
      v[nj][0] = s[nj][0] * scale + bv.x;
      v[nj][1] = s[nj][1] * scale + bv.y;
      v[nj][2] = s[nj][2] * scale + bv.z;
      v[nj][3] = s[nj][3] * scale + bv.w;
      mx = fmaxf(mx, fmaxf(fmaxf(v[nj][0], v[nj][1]), fmaxf(v[nj][2], v[nj][3])));
    }
    mx = fmaxf(mx, __shfl_xor(mx, 16, 64));
    mx = fmaxf(mx, __shfl_xor(mx, 32, 64));
    float sum = 0.f;
#pragma unroll
    for (int nj = 0; nj < 16; ++nj) {
      v[nj][0] = __expf(v[nj][0] - mx);
      v[nj][1] = __expf(v[nj][1] - mx);
      v[nj][2] = __expf(v[nj][2] - mx);
      v[nj][3] = __expf(v[nj][3] - mx);
      sum += (v[nj][0] + v[nj][1]) + (v[nj][2] + v[nj][3]);
    }
    sum += __shfl_xor(sum, 16, 64);
    sum += __shfl_xor(sum, 32, 64);
    const float inv = __frcp_rn(sum);
    float* prow = Pb + (size_t)row * N_ + kg * 4;
#pragma unroll
    for (int nj = 0; nj < 16; ++nj) {
      f32x4 o;
      o[0] = v[nj][0] * inv; o[1] = v[nj][1] * inv;
      o[2] = v[nj][2] * inv; o[3] = v[nj][3] * inv;
      __builtin_nontemporal_store(o, (f32x4*)(prow + nj * 16));
      bf16x4 pb;
      pb[0] = (bf16)o[0]; pb[1] = (bf16)o[1]; pb[2] = (bf16)o[2]; pb[3] = (bf16)o[3];
      *(bf16x4*)(Pw + ln * 520 + (nj * 16 + kg * 4) * 2) = pb;
    }
    f32x4 o0 = (f32x4){0.f,0.f,0.f,0.f}, o1 = (f32x4){0.f,0.f,0.f,0.f};
#pragma unroll
    for (int kt = 0; kt < 8; ++kt) {
      bf16x8 a = *(const bf16x8*)(Pw + ln * 520 + kt * 64 + kg * 16);
      int kc = kt * 4 + kg;
      bf16x8 b0 = *(const bf16x8*)((const char*)Vt + (size_t)ln * 512 + ((kc ^ (ln & 7)) << 4));
      bf16x8 b1 = *(const bf16x8*)((const char*)Vt + (size_t)(16 + ln) * 512 + ((kc ^ (ln & 7)) << 4));
      o0 = __builtin_amdgcn_mfma_f32_16x16x32_bf16(a, b0, o0, 0, 0, 0);
      o1 = __builtin_amdgcn_mfma_f32_16x16x32_bf16(a, b1, o1, 0, 0, 0);
    }
#pragma unroll
    for (int q = 0; q < 4; ++q) {
      int orow_i = i0 + kg * 4 + q;
      bf16* orow = out + (size_t)(bt * N_ + orow_i) * C_ + h * HD_;
      orow[ln]      = (bf16)o0[q];
      orow[16 + ln] = (bf16)o1[q];
    }
  }
}

// ---------- temporal attention: one block per (b,n), all 12 heads ----------
// Stage full qkv rows (b*T+t)*N+n, t=0..11 into LDS; 144 workers = (h,i).
#define TROW 1168   // 1152 + 16 pad (bf16 units)
__global__ __launch_bounds__(256) void k_attn_t(const bf16* __restrict__ qkv,
                                                bf16* __restrict__ out) {
  __shared__ bf16 S[T_ * TROW];
  const int bn = blockIdx.x;
  const int b = bn >> 8, n = bn & 255;
  const int tid = threadIdx.x;
  // stage: 12 rows x 144 chunks(16B) = 1728 chunks
  for (int c = tid; c < T_ * 144; c += 256) {
    int t = c / 144, off = (c - t * 144) * 8;
    bf16x8 vv = *(const bf16x8*)(qkv + (size_t)((b * T_ + t) * N_ + n) * QKV_ + off);
    *(bf16x8*)&S[t * TROW + off] = vv;
  }
  __syncthreads();
  if (tid < 144) {
    const int h = tid / 12, i = tid - h * 12;
    const int qo = h * HD_, ko = C_ + h * HD_, vo = 2 * C_ + h * HD_;
    float q[HD_];
#pragma unroll
    for (int d = 0; d < HD_; ++d) q[d] = (float)S[i * TROW + qo + d];
    float sv[T_];
    float m = -1e30f;
#pragma unroll
    for (int j = 0; j < T_; ++j) {
      float s = 0.f;
#pragma unroll
      for (int d = 0; d < HD_; ++d) s += q[d] * (float)S[j * TROW + ko + d];
      s *= 0.17677669529663687f;
      sv[j] = s; m = fmaxf(m, s);
    }
    float l = 0.f;
#pragma unroll
    for (int j = 0; j < T_; ++j) { sv[j] = __expf(sv[j] - m); l += sv[j]; }
    const float inv = 1.f / l;
    float o[HD_];
#pragma unroll
    for (int d = 0; d < HD_; ++d) o[d] = 0.f;
#pragma unroll
    for (int j = 0; j < T_; ++j) {
      float p = sv[j];
#pragma unroll
      for (int d = 0; d < HD_; ++d) o[d] += p * (float)S[j * TROW + vo + d];
    }
    bf16* orow = out + (size_t)((b * T_ + i) * N_ + n) * C_ + h * HD_;
#pragma unroll
    for (int d = 0; d < HD_; d += 2) {
      union { bf16 bb[2]; unsigned u; } pk;
      pk.bb[0] = (bf16)(o[d] * inv);
      pk.bb[1] = (bf16)(o[d + 1] * inv);
      *(unsigned*)&orow[d] = pk.u;
    }
  }
}

extern "C" void kernel_launch(void* const* d_in, const int* in_sizes, int n_in,
                              void* d_out, int out_size, void* d_ws, size_t ws_size,
                              hipStream_t stream) {
  const float* x_in   = (const float*)d_in[0];
  const float* c_in   = (const float*)d_in[1];
  const float* relb   = (const float*)d_in[2];
  const float* w_ada  = (const float*)d_in[3];
  const float* b_ada  = (const float*)d_in[4];
  const float* wqkv_s = (const float*)d_in[5];
  const float* bqkv_s = (const float*)d_in[6];
  const float* wproj_s= (const float*)d_in[7];
  const float* bproj_s= (const float*)d_in[8];
  const float* wqkv_t = (const float*)d_in[9];
  const float* bqkv_t = (const float*)d_in[10];
  const float* wproj_t= (const float*)d_in[11];
  const float* bproj_t= (const float*)d_in[12];
  const float* w1     = (const float*)d_in[13];
  const float* b1     = (const float*)d_in[14];
  const float* w2     = (const float*)d_in[15];
  const float* b2     = (const float*)d_in[16];

  float* Xout = (float*)d_out;
  float* attn = (float*)d_out + (size_t)M_ * C_;

  char* ws = (char*)d_ws;
  float* mod    = (float*)ws;
  bf16*  silu_b = (bf16*)(ws + 1769472);
  bf16*  Wb     = (bf16*)(ws + 1867776);
  bf16*  Bbuf   = (bf16*)(ws + 9240576);
  bf16*  Abuf   = (bf16*)(ws + 28114944);

  bf16* wqkv_s_b  = Wb;
  bf16* wproj_s_b = Wb + 442368;
  bf16* wqkv_t_b  = Wb + 589824;
  bf16* wproj_t_b = Wb + 1032192;
  bf16* w1_b      = Wb + 1179648;
  bf16* w2_b      = Wb + 1769472;
  bf16* wada_b    = Wb + 2359296;

  F2BArgs fa;
  fa.src[0] = wqkv_s;  fa.dst[0] = wqkv_s_b;  fa.n4[0] = 110592;
  fa.src[1] = wproj_s; fa.dst[1] = wproj_s_b; fa.n4[1] = 36864;
  fa.src[2] = wqkv_t;  fa.dst[2] = wqkv_t_b;  fa.n4[2] = 110592;
  fa.src[3] = wproj_t; fa.dst[3] = wproj_t_b; fa.n4[3] = 36864;
  fa.src[4] = w1;      fa.dst[4] = w1_b;      fa.n4[4] = 147456;
  fa.src[5] = w2;      fa.dst[5] = w2_b;      fa.n4[5] = 147456;
  fa.src[6] = w_ada;   fa.dst[6] = wada_b;    fa.n4[6] = 331776;
  fa.src[7] = c_in;    fa.dst[7] = silu_b;    fa.n4[7] = 12288;
  int total_blk = 0;
  for (int s = 0; s < 8; ++s) {
    fa.start[s] = total_blk;
    total_blk += (fa.n4[s] + 255) / 256;
  }
  fa.start[8] = total_blk;
  k_f2b_all<<<total_blk, 256, 0, stream>>>(fa);

  // 1. adaLN modulation via MFMA GEMM (M padded to 128)
  mfma_gemm<float, 0><<<27, 256, 0, stream>>>(
      silu_b, wada_b, b_ada, mod, 128, NINE_C, C_, nullptr, nullptr, 0, 27);

  // 2. spatial: LN+mod -> qkv -> fused attn -> proj + gated resid
  k_ln_mod<<<M_ / 4, 256, 0, stream>>>(x_in, mod, Bbuf, 0, 1);
  mfma_gemm<bf16, 0><<<(QKV_/128)*(M_/128), 256, 0, stream>>>(
      Bbuf, wqkv_s_b, bqkv_s, Abuf, M_, QKV_, C_, nullptr, nullptr, 0, QKV_/128);
  k_attn_fused<<<BT_ * NH_, 256, 0, stream>>>(Abuf, relb, attn, Bbuf);
  mfma_gemm<float, 2><<<(C_/128)*(M_/128), 256, 0, stream>>>(
      Bbuf, wproj_s_b, bproj_s, (float*)Xout, M_, C_, C_, x_in, mod, 2, C_/128);

  // 3. temporal (standard (bt,n) layout; transpose folded into attn_t gather)
  k_ln_mod<<<M_ / 4, 256, 0, stream>>>(Xout, mod, Bbuf, 3, 4);
  mfma_gemm<bf16, 0><<<(QKV_/128)*(M_/128), 256, 0, stream>>>(
      Bbuf, wqkv_t_b, bqkv_t, Abuf, M_, QKV_, C_, nullptr, nullptr, 0, QKV_/128);
  k_attn_t<<<B_ * N_, 256, 0, stream>>>(Abuf, Bbuf);
  mfma_gemm<float, 2><<<(C_/128)*(M_/128), 256, 0, stream>>>(
      Bbuf, wproj_t_b, bproj_t, (float*)Xout, M_, C_, C_, Xout, mod, 5, C_/128);

  // 4. MLP: LN+mod -> GEMM+GELU -> GEMM + gated resid (in place, NT final store)
  k_ln_mod<<<M_ / 4, 256, 0, stream>>>(Xout, mod, Bbuf, 6, 7);
  mfma_gemm<bf16, 1><<<(MLP_/128)*(M_/128), 256, 0, stream>>>(
      Bbuf, w1_b, b1, Abuf, M_, MLP_, C_, nullptr, nullptr, 0, MLP_/128);
  mfma_gemm<float, 4><<<(C_/128)*(M_/128), 256, 0, stream>>>(
      Abuf, w2_b, b2, (float*)Xout, M_, C_, MLP_, Xout, mod, 8, C_/128);
}